// Round 7
// baseline (388.486 us; speedup 1.0000x reference)
//
#include <hip/hip_runtime.h>

#define NN 100000
#define NE 1600000
#define FIN 256
#define FH 64
#define FC 16

#define NPB 512                     // nodes per bucket
#define NBKT ((NN + NPB - 1) / NPB) // 196
#define NBLK 256                    // edge-pass blocks
#define CHUNK (NE / NBLK)           // 6250 edges/block
#define CAP 12288                   // bucket_k LDS stash cap (mean 8163)
#define NB_GEMM1 ((NN + 127) / 128) // 782

typedef int v2i __attribute__((ext_vector_type(2)));
typedef int v4i __attribute__((ext_vector_type(4)));
typedef short s16x8 __attribute__((ext_vector_type(8)));       // 8 bf16
typedef float f32x4 __attribute__((ext_vector_type(4)));       // MFMA acc
typedef _Float16 h16x8 __attribute__((ext_vector_type(8)));    // 8 fp16 (16B)
typedef _Float16 h16x4 __attribute__((ext_vector_type(4)));    // 4 fp16 (8B)

__device__ __forceinline__ float4 add4(float4 a, float4 v) {
    a.x += v.x; a.y += v.y; a.z += v.z; a.w += v.w;
    return a;
}
__device__ __forceinline__ float4 xor_add4(float4 r, int m) {
    r.x += __shfl_xor(r.x, m, 64); r.y += __shfl_xor(r.y, m, 64);
    r.z += __shfl_xor(r.z, m, 64); r.w += __shfl_xor(r.w, m, 64);
    return r;
}
__device__ __forceinline__ h16x8 hz8() {
    h16x8 p;
    #pragma unroll
    for (int i = 0; i < 8; i++) p[i] = (_Float16)0.0f;
    return p;
}
__device__ __forceinline__ h16x4 hz4() {
    h16x4 p;
    #pragma unroll
    for (int i = 0; i < 4; i++) p[i] = (_Float16)0.0f;
    return p;
}

// RNE fp32 -> bf16
__device__ __forceinline__ unsigned short bf16rne(float f) {
    unsigned u = __float_as_uint(f);
    u += 0x7FFFu + ((u >> 16) & 1u);
    return (unsigned short)(u >> 16);
}
__device__ __forceinline__ void split8(const float* f, s16x8& hi, s16x8& lo) {
    #pragma unroll
    for (int i = 0; i < 8; i++) {
        unsigned u = __float_as_uint(f[i]);
        unsigned short h = (unsigned short)((u + 0x7FFFu + ((u >> 16) & 1u)) >> 16);
        float l = f[i] - __uint_as_float((unsigned)h << 16);
        unsigned ul = __float_as_uint(l);
        hi[i] = (short)h;
        lo[i] = (short)((ul + 0x7FFFu + ((ul >> 16) & 1u)) >> 16);
    }
}
// int64-vs-int32 edge_index layout (4 cached scalar loads)
__device__ __forceinline__ int is64(const int* __restrict__ ei) {
    return (ei[1] == 0) & (ei[3] == 0) & (ei[5] == 0) & (ei[7] == 0);
}

// ---- PASS A (fused): W1 frag prep (b<8) || per-(bucket,block) histogram ----
__global__ __launch_bounds__(256) void histprep_k(const int* __restrict__ ei,
                                                  const float* __restrict__ W,
                                                  unsigned short* __restrict__ Whi,
                                                  unsigned short* __restrict__ Wlo,
                                                  int* __restrict__ cnt) {
    const int b = blockIdx.x, t = threadIdx.x;
    if (b < 8) {      // W1 -> MFMA B-frag (bf16 hi/lo)
        int slot = b * 256 + t;            // (s,c,l)
        int l = slot & 63;
        int c = (slot >> 6) & 3;
        int s = slot >> 8;
        int k0 = s * 32 + (l >> 4) * 8;
        int col = c * 16 + (l & 15);
        #pragma unroll
        for (int i = 0; i < 8; i++) {
            float f = W[(k0 + i) * FH + col];
            unsigned short h = bf16rne(f);
            float lres = f - __uint_as_float((unsigned)h << 16);
            Whi[slot * 8 + i] = h;
            Wlo[slot * 8 + i] = bf16rne(lres);
        }
        return;
    }
    __shared__ int hist[NBKT];
    const int blk = b - 8;
    for (int j = t; j < NBKT; j += 256) hist[j] = 0;
    __syncthreads();
    int f = is64(ei);
    int base = blk * CHUNK;
    if (f) {
        for (int i = t; i < CHUNK; i += 256) {
            v2i p = *(const v2i*)&ei[2 * (NE + base + i)];
            atomicAdd(&hist[p.x >> 9], 1);
        }
    } else {
        for (int i = t; i < CHUNK; i += 256) {
            int d = ei[NE + base + i];
            atomicAdd(&hist[d >> 9], 1);
        }
    }
    __syncthreads();
    for (int j = t; j < NBKT; j += 256) cnt[j * NBLK + blk] = hist[j];   // [bucket][block]
}

// ---- scan: exclusive scan of cnt[196*256] (bucket-major) + bucketBase ------
__global__ __launch_bounds__(1024) void scanoff_k(int* __restrict__ cnt,
                                                  int* __restrict__ bucketBase) {
    __shared__ int s[1024];
    const int t = threadIdx.x;
    const int SEG = (NBKT * NBLK) / 1024;     // 49
    int base = t * SEG;
    int sum = 0;
    for (int i = 0; i < SEG; i++) sum += cnt[base + i];
    s[t] = sum; __syncthreads();
    for (int off = 1; off < 1024; off <<= 1) {
        int u = (t >= off) ? s[t - off] : 0;
        __syncthreads();
        s[t] += u;
        __syncthreads();
    }
    int run = s[t] - sum;                     // exclusive prefix
    for (int i = 0; i < SEG; i++) {
        int g = base + i;
        int v = cnt[g];
        cnt[g] = run;
        if ((g & (NBLK - 1)) == 0) bucketBase[g / NBLK] = run;
        run += v;
    }
    if (t == 0) bucketBase[NBKT] = NE;
}

// ---- FUSED: GEMM1 (b<782) || LDS-binned scatter (b>=782) -------------------
// Scat role: stash the block's 6250 edges in LDS ordered by target bucket,
// then write bucket-runs (avg 128B contiguous) -> coalesced stores instead of
// 1.6M scattered 4B transactions (the invisible wall).
__global__ __launch_bounds__(256, 4) void scatgemm_k(const int* __restrict__ ei,
                                                     const int* __restrict__ cnt,
                                                     int* __restrict__ sorted,
                                                     const float* __restrict__ x,
                                                     const unsigned short* __restrict__ Whi,
                                                     const unsigned short* __restrict__ Wlo,
                                                     _Float16* __restrict__ h1h) {
    __shared__ int stash[CHUNK];              // 25000 B
    __shared__ unsigned short bkt[CHUNK];     // 12500 B
    __shared__ int lhist[NBKT];
    __shared__ int lstart[NBKT];
    __shared__ int lcur[NBKT];
    __shared__ int sred[256];
    const int b = blockIdx.x, t = threadIdx.x;
    if (b >= NB_GEMM1) {                      // ---- scat role ----
        const int blk = b - NB_GEMM1;
        for (int j = t; j < NBKT; j += 256) lhist[j] = 0;
        __syncthreads();
        int f = is64(ei);
        int base = blk * CHUNK;
        if (f) {
            for (int i = t; i < CHUNK; i += 256) {
                v2i p = *(const v2i*)&ei[2 * (NE + base + i)];
                atomicAdd(&lhist[p.x >> 9], 1);
            }
        } else {
            for (int i = t; i < CHUNK; i += 256)
                atomicAdd(&lhist[ei[NE + base + i] >> 9], 1);
        }
        __syncthreads();
        int v = (t < NBKT) ? lhist[t] : 0;
        sred[t] = v; __syncthreads();
        for (int off = 1; off < 256; off <<= 1) {
            int u = (t >= off) ? sred[t - off] : 0;
            __syncthreads();
            sred[t] += u;
            __syncthreads();
        }
        if (t < NBKT) { lstart[t] = sred[t] - v; lcur[t] = sred[t] - v; }
        __syncthreads();
        if (f) {
            for (int i = t; i < CHUNK; i += 256) {
                int e = base + i;
                v2i ps = *(const v2i*)&ei[2 * e];
                v2i pd = *(const v2i*)&ei[2 * (NE + e)];
                int s = ps.x, d = pd.x;
                int bk = d >> 9;
                int pos = atomicAdd(&lcur[bk], 1);
                stash[pos] = s | ((d & (NPB - 1)) << 17);
                bkt[pos] = (unsigned short)bk;
            }
        } else {
            for (int i = t; i < CHUNK; i += 256) {
                int e = base + i;
                int s = ei[e], d = ei[NE + e];
                int bk = d >> 9;
                int pos = atomicAdd(&lcur[bk], 1);
                stash[pos] = s | ((d & (NPB - 1)) << 17);
                bkt[pos] = (unsigned short)bk;
            }
        }
        __syncthreads();
        for (int i = t; i < CHUNK; i += 256) {
            int bk = bkt[i];
            int g = cnt[bk * NBLK + blk] + (i - lstart[bk]);
            sorted[g] = stash[i];             // coalesced within each bucket-run
        }
        return;
    }
    // ---- GEMM1 role: h1h = fp16(x @ W1) (raw; dinv prescale in bucket_k) ---
    const int lane = t & 63;
    const int wid = t >> 6;
    const int mb = b * 128 + wid * 32;
    const int lr = lane & 15;
    const int lk = (lane >> 4) * 8;

    int ra0 = mb + lr;
    int ra1 = mb + 16 + lr;
    const float* pa0 = x + (size_t)(ra0 < NN ? ra0 : NN - 1) * FIN + lk;
    const float* pa1 = x + (size_t)(ra1 < NN ? ra1 : NN - 1) * FIN + lk;

    f32x4 acc[2][4] = {};

    for (int s = 0; s < 8; s++) {
        float fa0[8], fa1[8];
        float4 q;
        q = *(const float4*)(pa0 + s * 32);
        fa0[0] = q.x; fa0[1] = q.y; fa0[2] = q.z; fa0[3] = q.w;
        q = *(const float4*)(pa0 + s * 32 + 4);
        fa0[4] = q.x; fa0[5] = q.y; fa0[6] = q.z; fa0[7] = q.w;
        q = *(const float4*)(pa1 + s * 32);
        fa1[0] = q.x; fa1[1] = q.y; fa1[2] = q.z; fa1[3] = q.w;
        q = *(const float4*)(pa1 + s * 32 + 4);
        fa1[4] = q.x; fa1[5] = q.y; fa1[6] = q.z; fa1[7] = q.w;

        s16x8 a0h, a0l, a1h, a1l;
        split8(fa0, a0h, a0l);
        split8(fa1, a1h, a1l);

        #pragma unroll
        for (int c = 0; c < 4; c++) {
            s16x8 wh = *(const s16x8*)&Whi[((s * 4 + c) * 64 + lane) * 8];
            s16x8 wl = *(const s16x8*)&Wlo[((s * 4 + c) * 64 + lane) * 8];
            acc[0][c] = __builtin_amdgcn_mfma_f32_16x16x32_bf16(a0h, wh, acc[0][c], 0, 0, 0);
            acc[0][c] = __builtin_amdgcn_mfma_f32_16x16x32_bf16(a0l, wh, acc[0][c], 0, 0, 0);
            acc[0][c] = __builtin_amdgcn_mfma_f32_16x16x32_bf16(a0h, wl, acc[0][c], 0, 0, 0);
            acc[1][c] = __builtin_amdgcn_mfma_f32_16x16x32_bf16(a1h, wh, acc[1][c], 0, 0, 0);
            acc[1][c] = __builtin_amdgcn_mfma_f32_16x16x32_bf16(a1l, wh, acc[1][c], 0, 0, 0);
            acc[1][c] = __builtin_amdgcn_mfma_f32_16x16x32_bf16(a1h, wl, acc[1][c], 0, 0, 0);
        }
    }
    // D layout: col = lane&15, row = (lane>>4)*4 + v
    #pragma unroll
    for (int r = 0; r < 2; r++) {
        int rowb = mb + 16 * r + (lane >> 4) * 4;
        #pragma unroll
        for (int v = 0; v < 4; v++) {
            int row = rowb + v;
            if (row < NN) {
                #pragma unroll
                for (int c = 0; c < 4; c++)
                    h1h[(size_t)row * FH + 16 * c + lr] = (_Float16)acc[r][c][v];
            }
        }
    }
}

// ---- per-bucket counting sort: CSR + row_start + dinv + h1h prescale -------
__global__ __launch_bounds__(256) void bucket_k(const int* __restrict__ sorted,
                                                const int* __restrict__ bucketBase,
                                                int* __restrict__ csr,
                                                int* __restrict__ row_start,
                                                float* __restrict__ dinv,
                                                _Float16* __restrict__ h1h) {
    __shared__ int stash[CAP];       // 48 KB
    __shared__ int hist[NPB];
    __shared__ int startl[NPB];
    __shared__ int cursor[NPB];
    __shared__ int ss[256];
    const int t = threadIdx.x, b = blockIdx.x;
    const int nb0 = b * NPB;
    const int ncnt = (NN - nb0 < NPB) ? (NN - nb0) : NPB;
    const int ebase = bucketBase[b];
    const int ecnt = bucketBase[b + 1] - ebase;

    hist[t] = 0; hist[t + 256] = 0;
    __syncthreads();
    for (int i = t; i < ecnt; i += 256) {
        int v = sorted[ebase + i];
        if (i < CAP) stash[i] = v;
        atomicAdd(&hist[v >> 17], 1);
    }
    __syncthreads();
    // exclusive scan of hist[512] with 256 threads (pairwise)
    int a = hist[2 * t], c = hist[2 * t + 1];
    int p = a + c;
    ss[t] = p; __syncthreads();
    for (int off = 1; off < 256; off <<= 1) {
        int u = (t >= off) ? ss[t - off] : 0;
        __syncthreads();
        ss[t] += u;
        __syncthreads();
    }
    int ex = ss[t] - p;
    startl[2 * t] = ex;       startl[2 * t + 1] = ex + a;
    cursor[2 * t] = ex;       cursor[2 * t + 1] = ex + a;
    __syncthreads();
    for (int j = t; j < ncnt; j += 256) {
        row_start[nb0 + j] = ebase + startl[j];
        dinv[nb0 + j] = rsqrtf((float)(hist[j] + 1));
    }
    if (b == 0 && t == 0) row_start[NN] = NE;
    for (int i = t; i < ecnt; i += 256) {
        int v = (i < CAP) ? stash[i] : sorted[ebase + i];
        int dl = v >> 17;
        int r = atomicAdd(&cursor[dl], 1);
        csr[ebase + r] = v & 0x1FFFF;
    }
    // h1h prescale for this bucket's nodes (fp16 in-place, coalesced h16x8)
    h16x8* hp = (h16x8*)h1h;
    for (int q = t; q < ncnt * 8; q += 256) {
        int rl = q >> 3;
        _Float16 dvh = (_Float16)rsqrtf((float)(hist[rl] + 1));
        h16x8 v = hp[(size_t)(nb0 + rl) * 8 + (q & 7)];
        #pragma unroll
        for (int i = 0; i < 8; i++) v[i] = v[i] * dvh;
        hp[(size_t)(nb0 + rl) * 8 + (q & 7)] = v;
    }
}

// ---- FUSED agg1 + relu + GEMM2: packed-fp16 accumulate, fp32 flush/64 ------
__global__ __launch_bounds__(256) void agg1g_k(const int* __restrict__ csr,
                                               const int* __restrict__ row_start,
                                               const _Float16* __restrict__ h1h,
                                               const float* __restrict__ dinv,
                                               const float* __restrict__ b1,
                                               const float* __restrict__ W2,
                                               _Float16* __restrict__ h2h) {
    __shared__ float sW2[FH * FC];
    __shared__ float sp[4][FH];
    const int t = threadIdx.x;
    #pragma unroll
    for (int i = 0; i < 4; i++) sW2[t + 256 * i] = W2[t + 256 * i];
    __syncthreads();

    const int wid = t >> 6;
    const int n = blockIdx.x * 4 + wid;
    const int lane = t & 63;
    if (n >= NN) return;
    const int sg = lane >> 3;        // edge slot 0..7
    const int fl = lane & 7;         // feature octet 0..7
    const h16x8* hp = (const h16x8*)h1h;   // row n at hp[n*8]
    int s0 = row_start[n], s1 = row_start[n + 1];
    float facc[8] = {};
    for (int j0 = s0; j0 < s1; j0 += 64) {
        int idx = j0 + lane;
        int sl = (idx < s1) ? csr[idx] : 0;
        int cnt = s1 - j0; if (cnt > 64) cnt = 64;
        h16x8 pA = hz8(), pB = hz8();        // <=5 / <=4 fp16 adds per block
        int j = 0;
        for (; j + 16 <= cnt; j += 16) {
            int eA = __shfl(sl, j + sg, 64);
            int eB = __shfl(sl, j + 8 + sg, 64);
            pA += hp[eA * 8 + fl];           // v_pk_add_f16 x4
            pB += hp[eB * 8 + fl];
        }
        if (j + 8 <= cnt) {
            int eA = __shfl(sl, j + sg, 64);
            pA += hp[eA * 8 + fl];
            j += 8;
        }
        int rem = cnt - j;
        if (rem > 0) {                       // 1..7 edges, mask extra slots
            int jj = j + (sg < rem ? sg : 0);
            int eA = __shfl(sl, jj, 64);
            h16x8 v = hp[eA * 8 + fl];
            if (sg < rem) pB += v;
        }
        #pragma unroll
        for (int i = 0; i < 8; i++)
            facc[i] += (float)pA[i] + (float)pB[i];
    }
    #pragma unroll
    for (int i = 0; i < 8; i++) {
        float r = facc[i];
        r += __shfl_xor(r, 8, 64);
        r += __shfl_xor(r, 16, 64);
        r += __shfl_xor(r, 32, 64);
        facc[i] = r;                         // all lanes: full sum for feat fl*8+i
    }
    float dn = dinv[n];
    if (sg == 0) {
        h16x8 sv = hp[n * 8 + fl];           // self (already dinv-scaled)
        float4 p0, p1;
        float4 bq0 = *(const float4*)&b1[fl * 8];
        float4 bq1 = *(const float4*)&b1[fl * 8 + 4];
        p0.x = fmaxf(fmaf(facc[0] + (float)sv[0], dn, bq0.x), 0.f);
        p0.y = fmaxf(fmaf(facc[1] + (float)sv[1], dn, bq0.y), 0.f);
        p0.z = fmaxf(fmaf(facc[2] + (float)sv[2], dn, bq0.z), 0.f);
        p0.w = fmaxf(fmaf(facc[3] + (float)sv[3], dn, bq0.w), 0.f);
        p1.x = fmaxf(fmaf(facc[4] + (float)sv[4], dn, bq1.x), 0.f);
        p1.y = fmaxf(fmaf(facc[5] + (float)sv[5], dn, bq1.y), 0.f);
        p1.z = fmaxf(fmaf(facc[6] + (float)sv[6], dn, bq1.z), 0.f);
        p1.w = fmaxf(fmaf(facc[7] + (float)sv[7], dn, bq1.w), 0.f);
        *(float4*)&sp[wid][fl * 8] = p0;
        *(float4*)&sp[wid][fl * 8 + 4] = p1;
    }
    __builtin_amdgcn_s_waitcnt(0);           // drain lgkm within wave
    if (lane < FC) {
        float o = 0.f;
        #pragma unroll 8
        for (int k = 0; k < FH; k++)
            o = fmaf(sp[wid][k], sW2[k * FC + lane], o);
        h2h[n * FC + lane] = (_Float16)(o * dn);   // h2' = dinv*h2 (3.2MB)
    }
}

// ---- agg layer2: packed-fp16 accumulate, single flush ----------------------
__global__ __launch_bounds__(256) void agg2_k(const int* __restrict__ csr,
                                              const int* __restrict__ row_start,
                                              const _Float16* __restrict__ h2h,
                                              const float* __restrict__ dinv,
                                              const float* __restrict__ b2,
                                              float* __restrict__ out) {
    const int t = threadIdx.x;
    int n = blockIdx.x * 16 + (t >> 4);
    int l16 = t & 15;
    int base = t & 48;
    int q = (t >> 2) & 3;
    int c = t & 3;
    if (n >= NN) return;
    const h16x4* hp = (const h16x4*)h2h;     // row n at hp[n*4]
    int s0 = row_start[n], s1 = row_start[n + 1];
    h16x4 pA = hz4(), pB = hz4(), pC = hz4(), pD = hz4();   // <=8 adds each
    for (int j0 = s0; j0 < s1; j0 += 16) {
        int idx = j0 + l16;
        int sl = (idx < s1) ? csr[idx] : 0;
        int cnt = s1 - j0; if (cnt > 16) cnt = 16;
        int j = 0;
        if (j + 16 <= cnt) {
            int eA = __shfl(sl, base + j + q, 64);
            int eB = __shfl(sl, base + j + 4 + q, 64);
            int eC = __shfl(sl, base + j + 8 + q, 64);
            int eD = __shfl(sl, base + j + 12 + q, 64);
            pA += hp[eA * 4 + c];
            pB += hp[eB * 4 + c];
            pC += hp[eC * 4 + c];
            pD += hp[eD * 4 + c];
            j += 16;
        }
        if (j + 8 <= cnt) {
            int eA = __shfl(sl, base + j + q, 64);
            int eB = __shfl(sl, base + j + 4 + q, 64);
            pA += hp[eA * 4 + c];
            pB += hp[eB * 4 + c];
            j += 8;
        }
        if (j + 4 <= cnt) {
            int eA = __shfl(sl, base + j + q, 64);
            pA += hp[eA * 4 + c];
            j += 4;
        }
        int rem = cnt - j;
        if (rem > 0) {
            int jj = base + j + (q < rem ? q : 0);
            int eA = __shfl(sl, jj, 64);
            h16x4 v = hp[eA * 4 + c];
            if (q < rem) pD += v;
        }
    }
    float4 A = make_float4((float)pA[0] + (float)pB[0] + (float)pC[0] + (float)pD[0],
                           (float)pA[1] + (float)pB[1] + (float)pC[1] + (float)pD[1],
                           (float)pA[2] + (float)pB[2] + (float)pC[2] + (float)pD[2],
                           (float)pA[3] + (float)pB[3] + (float)pC[3] + (float)pD[3]);
    float4 r = xor_add4(A, 4);
    r = xor_add4(r, 8);
    if (q == 0) {
        float dn = dinv[n];
        h16x4 sv = hp[n * 4 + c];
        float4 bq = *(const float4*)&b2[c * 4];
        float4 p;
        p.x = fmaf(r.x + (float)sv[0], dn, bq.x);
        p.y = fmaf(r.y + (float)sv[1], dn, bq.y);
        p.z = fmaf(r.z + (float)sv[2], dn, bq.z);
        p.w = fmaf(r.w + (float)sv[3], dn, bq.w);
        *(float4*)&out[n * FC + c * 4] = p;
    }
}

extern "C" void kernel_launch(void* const* d_in, const int* in_sizes, int n_in,
                              void* d_out, int out_size, void* d_ws, size_t ws_size,
                              hipStream_t stream) {
    const float* x  = (const float*)d_in[0];
    const int*   ei = (const int*)d_in[1];
    const float* W1 = (const float*)d_in[2];
    const float* b1 = (const float*)d_in[3];
    const float* W2 = (const float*)d_in[4];
    const float* b2 = (const float*)d_in[5];
    float* out = (float*)d_out;

    char* ws = (char*)d_ws;
    int*   row_start  = (int*)(ws + 0);                           // 400 KB + 4
    float* dinv       = (float*)(ws + 512ull * 1024);             // 400 KB
    int*   bucketBase = (int*)(ws + 960ull * 1024);               // 788 B
    unsigned short* Whi = (unsigned short*)(ws + 1024ull * 1024); // 32 KB
    unsigned short* Wlo = (unsigned short*)(ws + 1088ull * 1024); // 32 KB
    int*   cnt        = (int*)(ws + 1152ull * 1024);              // 200 KB
    int*   csr        = (int*)(ws + 2048ull * 1024);              // 6.4 MB [bucket..agg2]
    int*   sorted     = (int*)(ws + 9216ull * 1024);              // 6.4 MB [scat..bucket]
    _Float16* h1h     = (_Float16*)(ws + 16384ull * 1024);        // 12.8 MB [scatgemm..agg1g]
    _Float16* h2h     = (_Float16*)(ws + 30720ull * 1024);        // 3.2 MB [agg1g..agg2]

    histprep_k<<<8 + NBLK, 256, 0, stream>>>(ei, W1, Whi, Wlo, cnt);
    scanoff_k<<<1, 1024, 0, stream>>>(cnt, bucketBase);
    scatgemm_k<<<NB_GEMM1 + NBLK, 256, 0, stream>>>(ei, cnt, sorted, x, Whi, Wlo, h1h);
    bucket_k<<<NBKT, 256, 0, stream>>>(sorted, bucketBase, csr, row_start, dinv, h1h);
    agg1g_k<<<(NN + 3) / 4, 256, 0, stream>>>(csr, row_start, h1h, dinv, b1, W2, h2h);
    agg2_k<<<(NN + 15) / 16, 256, 0, stream>>>(csr, row_start, h2h, dinv, b2, out);
}

// Round 8
// 376.764 us; speedup vs baseline: 1.0311x; 1.0311x over previous
//
#include <hip/hip_runtime.h>

#define NN 100000
#define NE 1600000
#define FIN 256
#define FH 64
#define FC 16

#define NPB 512                     // nodes per bucket
#define NBKT ((NN + NPB - 1) / NPB) // 196
#define NBLK 256                    // edge-pass blocks
#define CHUNK (NE / NBLK)           // 6250 edges/block
#define CAP 12288                   // bucket_k LDS stash cap (mean 8163)
#define NB_GEMM1 ((NN + 127) / 128) // 782

typedef int v2i __attribute__((ext_vector_type(2)));
typedef short s16x8 __attribute__((ext_vector_type(8)));       // 8 bf16
typedef float f32x4 __attribute__((ext_vector_type(4)));       // MFMA acc
typedef _Float16 h16x8 __attribute__((ext_vector_type(8)));    // 8 fp16 (16B)
typedef _Float16 h16x4 __attribute__((ext_vector_type(4)));    // 4 fp16 (8B)
typedef _Float16 h16x2 __attribute__((ext_vector_type(2)));    // 2 fp16 (4B)

__device__ __forceinline__ h16x8 hz8() {
    h16x8 p;
    #pragma unroll
    for (int i = 0; i < 8; i++) p[i] = (_Float16)0.0f;
    return p;
}
__device__ __forceinline__ h16x4 hz4() {
    h16x4 p;
    #pragma unroll
    for (int i = 0; i < 4; i++) p[i] = (_Float16)0.0f;
    return p;
}

// RNE fp32 -> bf16
__device__ __forceinline__ unsigned short bf16rne(float f) {
    unsigned u = __float_as_uint(f);
    u += 0x7FFFu + ((u >> 16) & 1u);
    return (unsigned short)(u >> 16);
}
__device__ __forceinline__ void split8(const float* f, s16x8& hi, s16x8& lo) {
    #pragma unroll
    for (int i = 0; i < 8; i++) {
        unsigned u = __float_as_uint(f[i]);
        unsigned short h = (unsigned short)((u + 0x7FFFu + ((u >> 16) & 1u)) >> 16);
        float l = f[i] - __uint_as_float((unsigned)h << 16);
        unsigned ul = __float_as_uint(l);
        hi[i] = (short)h;
        lo[i] = (short)((ul + 0x7FFFu + ((ul >> 16) & 1u)) >> 16);
    }
}
// int64-vs-int32 edge_index layout (4 cached scalar loads)
__device__ __forceinline__ int is64(const int* __restrict__ ei) {
    return (ei[1] == 0) & (ei[3] == 0) & (ei[5] == 0) & (ei[7] == 0);
}

// ---- PASS A (fused): W1 frag prep (b<8) || per-(bucket,block) histogram ----
__global__ __launch_bounds__(256) void histprep_k(const int* __restrict__ ei,
                                                  const float* __restrict__ W,
                                                  unsigned short* __restrict__ Whi,
                                                  unsigned short* __restrict__ Wlo,
                                                  int* __restrict__ cnt) {
    const int b = blockIdx.x, t = threadIdx.x;
    if (b < 8) {      // W1 -> MFMA B-frag (bf16 hi/lo)
        int slot = b * 256 + t;            // (s,c,l)
        int l = slot & 63;
        int c = (slot >> 6) & 3;
        int s = slot >> 8;
        int k0 = s * 32 + (l >> 4) * 8;
        int col = c * 16 + (l & 15);
        #pragma unroll
        for (int i = 0; i < 8; i++) {
            float f = W[(k0 + i) * FH + col];
            unsigned short h = bf16rne(f);
            float lres = f - __uint_as_float((unsigned)h << 16);
            Whi[slot * 8 + i] = h;
            Wlo[slot * 8 + i] = bf16rne(lres);
        }
        return;
    }
    __shared__ int hist[NBKT];
    const int blk = b - 8;
    for (int j = t; j < NBKT; j += 256) hist[j] = 0;
    __syncthreads();
    int f = is64(ei);
    int base = blk * CHUNK;
    if (f) {
        for (int i = t; i < CHUNK; i += 256) {
            v2i p = *(const v2i*)&ei[2 * (NE + base + i)];
            atomicAdd(&hist[p.x >> 9], 1);
        }
    } else {
        for (int i = t; i < CHUNK; i += 256) {
            int d = ei[NE + base + i];
            atomicAdd(&hist[d >> 9], 1);
        }
    }
    __syncthreads();
    for (int j = t; j < NBKT; j += 256) cnt[j * NBLK + blk] = hist[j];   // [bucket][block]
}

// ---- bucket totals: block b reduces its cnt row (coalesced) ----------------
__global__ __launch_bounds__(256) void bsum_k(const int* __restrict__ cnt,
                                              int* __restrict__ bucketTot) {
    __shared__ int red[256];
    int b = blockIdx.x, t = threadIdx.x;
    red[t] = cnt[b * NBLK + t];
    __syncthreads();
    for (int off = 128; off > 0; off >>= 1) {
        if (t < off) red[t] += red[t + off];
        __syncthreads();
    }
    if (t == 0) bucketTot[b] = red[0];
}

// ---- 196-entry exclusive scan -> bucketBase --------------------------------
__global__ __launch_bounds__(256) void bscan_k(const int* __restrict__ bucketTot,
                                               int* __restrict__ bucketBase) {
    __shared__ int s[256];
    int t = threadIdx.x;
    int v = (t < NBKT) ? bucketTot[t] : 0;
    s[t] = v; __syncthreads();
    for (int off = 1; off < 256; off <<= 1) {
        int u = (t >= off) ? s[t - off] : 0;
        __syncthreads();
        s[t] += u;
        __syncthreads();
    }
    if (t < NBKT) bucketBase[t] = s[t] - v;   // exclusive
    if (t == 0) bucketBase[NBKT] = NE;
}

// ---- per-bucket-row exclusive scan + global offset (coalesced) -------------
__global__ __launch_bounds__(256) void brow_k(int* __restrict__ cnt,
                                              const int* __restrict__ bucketBase) {
    __shared__ int s[256];
    int b = blockIdx.x, t = threadIdx.x;
    int v = cnt[b * NBLK + t];
    s[t] = v; __syncthreads();
    for (int off = 1; off < 256; off <<= 1) {
        int u = (t >= off) ? s[t - off] : 0;
        __syncthreads();
        s[t] += u;
        __syncthreads();
    }
    cnt[b * NBLK + t] = bucketBase[b] + s[t] - v;
}

// ---- FUSED: GEMM1 (b<782) || LDS-binned scatter (b>=782) -------------------
__global__ __launch_bounds__(256, 4) void scatgemm_k(const int* __restrict__ ei,
                                                     const int* __restrict__ cnt,
                                                     int* __restrict__ sorted,
                                                     const float* __restrict__ x,
                                                     const unsigned short* __restrict__ Whi,
                                                     const unsigned short* __restrict__ Wlo,
                                                     _Float16* __restrict__ h1h) {
    __shared__ int stash[CHUNK];              // 25000 B
    __shared__ unsigned short bkt[CHUNK];     // 12500 B
    __shared__ int lhist[NBKT];
    __shared__ int lstart[NBKT];
    __shared__ int lcur[NBKT];
    __shared__ int sred[256];
    const int b = blockIdx.x, t = threadIdx.x;
    if (b >= NB_GEMM1) {                      // ---- scat role ----
        const int blk = b - NB_GEMM1;
        for (int j = t; j < NBKT; j += 256) lhist[j] = 0;
        __syncthreads();
        int f = is64(ei);
        int base = blk * CHUNK;
        if (f) {
            for (int i = t; i < CHUNK; i += 256) {
                v2i p = *(const v2i*)&ei[2 * (NE + base + i)];
                atomicAdd(&lhist[p.x >> 9], 1);
            }
        } else {
            for (int i = t; i < CHUNK; i += 256)
                atomicAdd(&lhist[ei[NE + base + i] >> 9], 1);
        }
        __syncthreads();
        int v = (t < NBKT) ? lhist[t] : 0;
        sred[t] = v; __syncthreads();
        for (int off = 1; off < 256; off <<= 1) {
            int u = (t >= off) ? sred[t - off] : 0;
            __syncthreads();
            sred[t] += u;
            __syncthreads();
        }
        if (t < NBKT) { lstart[t] = sred[t] - v; lcur[t] = sred[t] - v; }
        __syncthreads();
        if (f) {
            for (int i = t; i < CHUNK; i += 256) {
                int e = base + i;
                v2i ps = *(const v2i*)&ei[2 * e];
                v2i pd = *(const v2i*)&ei[2 * (NE + e)];
                int s = ps.x, d = pd.x;
                int bk = d >> 9;
                int pos = atomicAdd(&lcur[bk], 1);
                stash[pos] = s | ((d & (NPB - 1)) << 17);
                bkt[pos] = (unsigned short)bk;
            }
        } else {
            for (int i = t; i < CHUNK; i += 256) {
                int e = base + i;
                int s = ei[e], d = ei[NE + e];
                int bk = d >> 9;
                int pos = atomicAdd(&lcur[bk], 1);
                stash[pos] = s | ((d & (NPB - 1)) << 17);
                bkt[pos] = (unsigned short)bk;
            }
        }
        __syncthreads();
        for (int i = t; i < CHUNK; i += 256) {
            int bk = bkt[i];
            int g = cnt[bk * NBLK + blk] + (i - lstart[bk]);
            sorted[g] = stash[i];             // coalesced within each bucket-run
        }
        return;
    }
    // ---- GEMM1 role: h1h = fp16(x @ W1) (raw; dinv prescale in bucket_k) ---
    const int lane = t & 63;
    const int wid = t >> 6;
    const int mb = b * 128 + wid * 32;
    const int lr = lane & 15;
    const int lk = (lane >> 4) * 8;

    int ra0 = mb + lr;
    int ra1 = mb + 16 + lr;
    const float* pa0 = x + (size_t)(ra0 < NN ? ra0 : NN - 1) * FIN + lk;
    const float* pa1 = x + (size_t)(ra1 < NN ? ra1 : NN - 1) * FIN + lk;

    f32x4 acc[2][4] = {};

    for (int s = 0; s < 8; s++) {
        float fa0[8], fa1[8];
        float4 q;
        q = *(const float4*)(pa0 + s * 32);
        fa0[0] = q.x; fa0[1] = q.y; fa0[2] = q.z; fa0[3] = q.w;
        q = *(const float4*)(pa0 + s * 32 + 4);
        fa0[4] = q.x; fa0[5] = q.y; fa0[6] = q.z; fa0[7] = q.w;
        q = *(const float4*)(pa1 + s * 32);
        fa1[0] = q.x; fa1[1] = q.y; fa1[2] = q.z; fa1[3] = q.w;
        q = *(const float4*)(pa1 + s * 32 + 4);
        fa1[4] = q.x; fa1[5] = q.y; fa1[6] = q.z; fa1[7] = q.w;

        s16x8 a0h, a0l, a1h, a1l;
        split8(fa0, a0h, a0l);
        split8(fa1, a1h, a1l);

        #pragma unroll
        for (int c = 0; c < 4; c++) {
            s16x8 wh = *(const s16x8*)&Whi[((s * 4 + c) * 64 + lane) * 8];
            s16x8 wl = *(const s16x8*)&Wlo[((s * 4 + c) * 64 + lane) * 8];
            acc[0][c] = __builtin_amdgcn_mfma_f32_16x16x32_bf16(a0h, wh, acc[0][c], 0, 0, 0);
            acc[0][c] = __builtin_amdgcn_mfma_f32_16x16x32_bf16(a0l, wh, acc[0][c], 0, 0, 0);
            acc[0][c] = __builtin_amdgcn_mfma_f32_16x16x32_bf16(a0h, wl, acc[0][c], 0, 0, 0);
            acc[1][c] = __builtin_amdgcn_mfma_f32_16x16x32_bf16(a1h, wh, acc[1][c], 0, 0, 0);
            acc[1][c] = __builtin_amdgcn_mfma_f32_16x16x32_bf16(a1l, wh, acc[1][c], 0, 0, 0);
            acc[1][c] = __builtin_amdgcn_mfma_f32_16x16x32_bf16(a1h, wl, acc[1][c], 0, 0, 0);
        }
    }
    // D layout: col = lane&15, row = (lane>>4)*4 + v
    #pragma unroll
    for (int r = 0; r < 2; r++) {
        int rowb = mb + 16 * r + (lane >> 4) * 4;
        #pragma unroll
        for (int v = 0; v < 4; v++) {
            int row = rowb + v;
            if (row < NN) {
                #pragma unroll
                for (int c = 0; c < 4; c++)
                    h1h[(size_t)row * FH + 16 * c + lr] = (_Float16)acc[r][c][v];
            }
        }
    }
}

// ---- per-bucket counting sort: CSR + row_start + dinv + h1h prescale -------
__global__ __launch_bounds__(256) void bucket_k(const int* __restrict__ sorted,
                                                const int* __restrict__ bucketBase,
                                                int* __restrict__ csr,
                                                int* __restrict__ row_start,
                                                float* __restrict__ dinv,
                                                _Float16* __restrict__ h1h) {
    __shared__ int stash[CAP];       // 48 KB
    __shared__ int hist[NPB];
    __shared__ int startl[NPB];
    __shared__ int cursor[NPB];
    __shared__ int ss[256];
    const int t = threadIdx.x, b = blockIdx.x;
    const int nb0 = b * NPB;
    const int ncnt = (NN - nb0 < NPB) ? (NN - nb0) : NPB;
    const int ebase = bucketBase[b];
    const int ecnt = bucketBase[b + 1] - ebase;

    hist[t] = 0; hist[t + 256] = 0;
    __syncthreads();
    for (int i = t; i < ecnt; i += 256) {
        int v = sorted[ebase + i];
        if (i < CAP) stash[i] = v;
        atomicAdd(&hist[v >> 17], 1);
    }
    __syncthreads();
    // exclusive scan of hist[512] with 256 threads (pairwise)
    int a = hist[2 * t], c = hist[2 * t + 1];
    int p = a + c;
    ss[t] = p; __syncthreads();
    for (int off = 1; off < 256; off <<= 1) {
        int u = (t >= off) ? ss[t - off] : 0;
        __syncthreads();
        ss[t] += u;
        __syncthreads();
    }
    int ex = ss[t] - p;
    startl[2 * t] = ex;       startl[2 * t + 1] = ex + a;
    cursor[2 * t] = ex;       cursor[2 * t + 1] = ex + a;
    __syncthreads();
    for (int j = t; j < ncnt; j += 256) {
        row_start[nb0 + j] = ebase + startl[j];
        dinv[nb0 + j] = rsqrtf((float)(hist[j] + 1));
    }
    if (b == 0 && t == 0) row_start[NN] = NE;
    for (int i = t; i < ecnt; i += 256) {
        int v = (i < CAP) ? stash[i] : sorted[ebase + i];
        int dl = v >> 17;
        int r = atomicAdd(&cursor[dl], 1);
        csr[ebase + r] = v & 0x1FFFF;
    }
    // h1h prescale for this bucket's nodes (fp16 in-place, coalesced h16x8)
    h16x8* hp = (h16x8*)h1h;
    for (int q = t; q < ncnt * 8; q += 256) {
        int rl = q >> 3;
        _Float16 dvh = (_Float16)rsqrtf((float)(hist[rl] + 1));
        h16x8 v = hp[(size_t)(nb0 + rl) * 8 + (q & 7)];
        #pragma unroll
        for (int i = 0; i < 8; i++) v[i] = v[i] * dvh;
        hp[(size_t)(nb0 + rl) * 8 + (q & 7)] = v;
    }
}

// ---- FUSED agg1 + relu + GEMM2: zero-LDS, register-W2, direct csr loads ----
// Wave = node. lane = sg*8+fl: sg = edge slot / output pair, fl = feat octet.
// Chain: csr broadcast load -> gather -> pk-fp16 add (whole loop) ->
// fp32 reduce across sg -> per-lane relu -> 16 reg-FMA GEMM2 -> fl-reduce.
__global__ __launch_bounds__(256) void agg1g_k(const int* __restrict__ csr,
                                               const int* __restrict__ row_start,
                                               const _Float16* __restrict__ h1h,
                                               const float* __restrict__ dinv,
                                               const float* __restrict__ b1,
                                               const float* __restrict__ W2,
                                               _Float16* __restrict__ h2h) {
    const int t = threadIdx.x;
    const int wid = t >> 6;
    const int lane = t & 63;
    const int sg = lane >> 3;        // 0..7
    const int fl = lane & 7;         // 0..7
    // per-lane constants (uniform across nodes; loaded once, stay in VGPRs)
    float w2r0[8], w2r1[8], br[8];
    #pragma unroll
    for (int i = 0; i < 8; i++) {
        float2 w = *(const float2*)&W2[(fl * 8 + i) * FC + 2 * sg];
        w2r0[i] = w.x; w2r1[i] = w.y;
        br[i] = b1[fl * 8 + i];
    }
    const int n = blockIdx.x * 4 + wid;
    if (n >= NN) return;
    const h16x8* hp = (const h16x8*)h1h;
    int s0 = row_start[n], s1 = row_start[n + 1];
    h16x8 pA = hz8(), pB = hz8();    // chain length <= ceil(deg/16) ~ 1-4 adds
    for (int j = s0; j < s1; j += 16) {
        int e1 = j + sg, e2 = j + 8 + sg;
        int c1 = csr[(e1 < s1) ? e1 : s1 - 1];   // 8 lanes share addr (bcast)
        int c2 = csr[(e2 < s1) ? e2 : s1 - 1];
        h16x8 vA = hp[(size_t)c1 * 8 + fl];
        h16x8 vB = hp[(size_t)c2 * 8 + fl];
        if (e1 < s1) pA += vA;
        if (e2 < s1) pB += vB;
    }
    float facc[8];
    #pragma unroll
    for (int i = 0; i < 8; i++) facc[i] = (float)pA[i] + (float)pB[i];
    #pragma unroll
    for (int i = 0; i < 8; i++) {
        facc[i] += __shfl_xor(facc[i], 8, 64);
        facc[i] += __shfl_xor(facc[i], 16, 64);
        facc[i] += __shfl_xor(facc[i], 32, 64);   // all lanes: full octet sums
    }
    float dn = dinv[n];
    h16x8 sv = hp[(size_t)n * 8 + fl];            // self (already dinv-scaled)
    float o0 = 0.f, o1 = 0.f;
    #pragma unroll
    for (int i = 0; i < 8; i++) {
        float pi = fmaxf(fmaf(facc[i] + (float)sv[i], dn, br[i]), 0.f);
        o0 = fmaf(pi, w2r0[i], o0);
        o1 = fmaf(pi, w2r1[i], o1);
    }
    o0 += __shfl_xor(o0, 1, 64); o1 += __shfl_xor(o1, 1, 64);
    o0 += __shfl_xor(o0, 2, 64); o1 += __shfl_xor(o1, 2, 64);
    o0 += __shfl_xor(o0, 4, 64); o1 += __shfl_xor(o1, 4, 64);
    if (fl == 0) {
        h16x2 r;
        r[0] = (_Float16)(o0 * dn);
        r[1] = (_Float16)(o1 * dn);
        *(h16x2*)&h2h[(size_t)n * FC + 2 * sg] = r;   // h2' = dinv*h2
    }
}

// ---- agg layer2: direct csr loads, whole-loop fp16 accumulate --------------
// 16 lanes/node: q = edge slot 0..3, c = feature quad 0..3 (h16x4, 8B).
__global__ __launch_bounds__(256) void agg2_k(const int* __restrict__ csr,
                                              const int* __restrict__ row_start,
                                              const _Float16* __restrict__ h2h,
                                              const float* __restrict__ dinv,
                                              const float* __restrict__ b2,
                                              float* __restrict__ out) {
    const int t = threadIdx.x;
    const int n = blockIdx.x * 16 + (t >> 4);
    const int q = (t >> 2) & 3;
    const int c = t & 3;
    float4 bq = *(const float4*)&b2[c * 4];      // uniform, cached
    if (n >= NN) return;
    const h16x4* hp = (const h16x4*)h2h;
    int s0 = row_start[n], s1 = row_start[n + 1];
    h16x4 pA = hz4(), pB = hz4();                // chain <= ceil(deg/8) adds
    for (int j = s0; j < s1; j += 8) {
        int e1 = j + q, e2 = j + 4 + q;
        int c1 = csr[(e1 < s1) ? e1 : s1 - 1];
        int c2 = csr[(e2 < s1) ? e2 : s1 - 1];
        h16x4 vA = hp[(size_t)c1 * 4 + c];
        h16x4 vB = hp[(size_t)c2 * 4 + c];
        if (e1 < s1) pA += vA;
        if (e2 < s1) pB += vB;
    }
    float r0 = (float)pA[0] + (float)pB[0];
    float r1 = (float)pA[1] + (float)pB[1];
    float r2 = (float)pA[2] + (float)pB[2];
    float r3 = (float)pA[3] + (float)pB[3];
    r0 += __shfl_xor(r0, 4, 64); r1 += __shfl_xor(r1, 4, 64);
    r2 += __shfl_xor(r2, 4, 64); r3 += __shfl_xor(r3, 4, 64);
    r0 += __shfl_xor(r0, 8, 64); r1 += __shfl_xor(r1, 8, 64);
    r2 += __shfl_xor(r2, 8, 64); r3 += __shfl_xor(r3, 8, 64);
    if (q == 0) {
        float dn = dinv[n];
        h16x4 sv = hp[(size_t)n * 4 + c];        // self (already dinv-scaled)
        float4 p;
        p.x = fmaf(r0 + (float)sv[0], dn, bq.x);
        p.y = fmaf(r1 + (float)sv[1], dn, bq.y);
        p.z = fmaf(r2 + (float)sv[2], dn, bq.z);
        p.w = fmaf(r3 + (float)sv[3], dn, bq.w);
        *(float4*)&out[(size_t)n * FC + c * 4] = p;
    }
}

extern "C" void kernel_launch(void* const* d_in, const int* in_sizes, int n_in,
                              void* d_out, int out_size, void* d_ws, size_t ws_size,
                              hipStream_t stream) {
    const float* x  = (const float*)d_in[0];
    const int*   ei = (const int*)d_in[1];
    const float* W1 = (const float*)d_in[2];
    const float* b1 = (const float*)d_in[3];
    const float* W2 = (const float*)d_in[4];
    const float* b2 = (const float*)d_in[5];
    float* out = (float*)d_out;

    char* ws = (char*)d_ws;
    int*   row_start  = (int*)(ws + 0);                           // 400 KB + 4
    float* dinv       = (float*)(ws + 512ull * 1024);             // 400 KB
    int*   bucketBase = (int*)(ws + 960ull * 1024);               // 788 B
    int*   bucketTot  = (int*)(ws + 968ull * 1024);               // 784 B
    unsigned short* Whi = (unsigned short*)(ws + 1024ull * 1024); // 32 KB
    unsigned short* Wlo = (unsigned short*)(ws + 1088ull * 1024); // 32 KB
    int*   cnt        = (int*)(ws + 1152ull * 1024);              // 200 KB
    int*   csr        = (int*)(ws + 2048ull * 1024);              // 6.4 MB [bucket..agg2]
    int*   sorted     = (int*)(ws + 9216ull * 1024);              // 6.4 MB [scat..bucket]
    _Float16* h1h     = (_Float16*)(ws + 16384ull * 1024);        // 12.8 MB [scatgemm..agg1g]
    _Float16* h2h     = (_Float16*)(ws + 30720ull * 1024);        // 3.2 MB [agg1g..agg2]

    histprep_k<<<8 + NBLK, 256, 0, stream>>>(ei, W1, Whi, Wlo, cnt);
    bsum_k<<<NBKT, 256, 0, stream>>>(cnt, bucketTot);
    bscan_k<<<1, 256, 0, stream>>>(bucketTot, bucketBase);
    brow_k<<<NBKT, 256, 0, stream>>>(cnt, bucketBase);
    scatgemm_k<<<NB_GEMM1 + NBLK, 256, 0, stream>>>(ei, cnt, sorted, x, Whi, Wlo, h1h);
    bucket_k<<<NBKT, 256, 0, stream>>>(sorted, bucketBase, csr, row_start, dinv, h1h);
    agg1g_k<<<(NN + 3) / 4, 256, 0, stream>>>(csr, row_start, h1h, dinv, b1, W2, h2h);
    agg2_k<<<(NN + 15) / 16, 256, 0, stream>>>(csr, row_start, h2h, dinv, b2, out);
}